// Round 1
// baseline (262.373 us; speedup 1.0000x reference)
//
#include <hip/hip_runtime.h>

#define D_ 160
#define H_ 192
#define W_ 160
#define V_ (D_*H_*W_)          // 4,915,200 voxels per batch
#define NTOT (2*V_)            // 9,830,400 total
#define TW 32
#define TH 32
#define RW 40                  // TW + 8 halo
#define RH 40                  // TH + 8 halo
#define CHUNK 32               // D-chunk per thread in pass2

// ---------------------------------------------------------------------------
// Pass 1: for one d-slice, compute the five 1x9x9 (W then H) partial window
// sums of {I, J, I*I, J*J, I*J} for a 32x32 tile, using an LDS-staged
// 40x40 halo region. Zero padding outside the volume.
// ---------------------------------------------------------------------------
__global__ __launch_bounds__(256) void pass1_wh(const float* __restrict__ I,
                                                const float* __restrict__ J,
                                                float* __restrict__ F) {
  __shared__ float sI[RH][RW];
  __shared__ float sJ[RH][RW];
  __shared__ float wsum[5][RH][TW];

  const int tid = threadIdx.x;
  const int w0 = blockIdx.x * TW;   // 5 tiles
  const int h0 = blockIdx.y * TH;   // 6 tiles
  const int d  = blockIdx.z;        // 160 slices

  const float* Ip = I + (size_t)d * (H_ * W_);
  const float* Jp = J + (size_t)d * (H_ * W_);

  // Stage halo region [h0-4, h0+35] x [w0-4, w0+35], zero outside volume.
  for (int idx = tid; idx < RH * RW; idx += 256) {
    int rj = idx / RW, ri = idx % RW;
    int h = h0 - 4 + rj, w = w0 - 4 + ri;
    float vi = 0.f, vj = 0.f;
    if ((unsigned)h < (unsigned)H_ && (unsigned)w < (unsigned)W_) {
      vi = Ip[h * W_ + w];
      vj = Jp[h * W_ + w];
    }
    sI[rj][ri] = vi;
    sJ[rj][ri] = vj;
  }
  __syncthreads();

  // W-direction 9-sum, products computed on the fly.
  for (int idx = tid; idx < RH * TW; idx += 256) {
    int rj = idx / TW, i = idx % TW;
    float s0 = 0.f, s1 = 0.f, s2 = 0.f, s3 = 0.f, s4 = 0.f;
#pragma unroll
    for (int t = 0; t < 9; ++t) {
      float a = sI[rj][i + t];
      float b = sJ[rj][i + t];
      s0 += a; s1 += b; s2 += a * a; s3 += b * b; s4 += a * b;
    }
    wsum[0][rj][i] = s0;
    wsum[1][rj][i] = s1;
    wsum[2][rj][i] = s2;
    wsum[3][rj][i] = s3;
    wsum[4][rj][i] = s4;
  }
  __syncthreads();

  // H-direction 9-sum, write 5 fields to workspace.
  for (int idx = tid; idx < TH * TW; idx += 256) {
    int j = idx / TW, i = idx % TW;
    float r0 = 0.f, r1 = 0.f, r2 = 0.f, r3 = 0.f, r4 = 0.f;
#pragma unroll
    for (int t = 0; t < 9; ++t) {
      r0 += wsum[0][j + t][i];
      r1 += wsum[1][j + t][i];
      r2 += wsum[2][j + t][i];
      r3 += wsum[3][j + t][i];
      r4 += wsum[4][j + t][i];
    }
    size_t o = (size_t)d * (H_ * W_) + (size_t)(h0 + j) * W_ + (w0 + i);
    F[0 * (size_t)V_ + o] = r0;
    F[1 * (size_t)V_ + o] = r1;
    F[2 * (size_t)V_ + o] = r2;
    F[3 * (size_t)V_ + o] = r3;
    F[4 * (size_t)V_ + o] = r4;
  }
}

// ---------------------------------------------------------------------------
// Pass 2: finish the D-direction 9-sum with a running window per (h,w)
// column chunk, compute cc per voxel, reduce to a double accumulator.
// ---------------------------------------------------------------------------
__global__ __launch_bounds__(256) void pass2_d(const float* __restrict__ F,
                                               double* __restrict__ acc) {
  const int tid = blockIdx.x * 256 + threadIdx.x;
  const int plane = H_ * W_;               // 30720
  const int nchunk = D_ / CHUNK;           // 5
  float local = 0.f;

  if (tid < nchunk * plane) {
    const int col = tid % plane;           // h*W + w (coalesced across lanes)
    const int d0 = (tid / plane) * CHUNK;
    const float* base = F + col;

    float s0 = 0.f, s1 = 0.f, s2 = 0.f, s3 = 0.f, s4 = 0.f;
    // Warm-up: window for d0 covers [d0-4, d0+4]; preload [d0-4, d0+3].
    for (int dd = d0 - 4; dd < d0 + 4; ++dd) {
      if (dd >= 0) {
        size_t o = (size_t)dd * plane;
        s0 += base[0 * (size_t)V_ + o];
        s1 += base[1 * (size_t)V_ + o];
        s2 += base[2 * (size_t)V_ + o];
        s3 += base[3 * (size_t)V_ + o];
        s4 += base[4 * (size_t)V_ + o];
      }
    }

    const float inv = 1.f / 729.f;
    for (int d = d0; d < d0 + CHUNK; ++d) {
      int da = d + 4;
      if (da < D_) {
        size_t o = (size_t)da * plane;
        s0 += base[0 * (size_t)V_ + o];
        s1 += base[1 * (size_t)V_ + o];
        s2 += base[2 * (size_t)V_ + o];
        s3 += base[3 * (size_t)V_ + o];
        s4 += base[4 * (size_t)V_ + o];
      }
      float uI = s0 * inv, uJ = s1 * inv;
      float cross = s4 - uJ * s0 - uI * s1 + uI * uJ * 729.f;
      float Iv = s2 - 2.f * uI * s0 + uI * uI * 729.f;
      float Jv = s3 - 2.f * uJ * s1 + uJ * uJ * 729.f;
      float cc = cross * cross / (Iv * Jv + 1e-5f);
      local += cc;
      int ds = d - 4;
      if (ds >= 0) {
        size_t o = (size_t)ds * plane;
        s0 -= base[0 * (size_t)V_ + o];
        s1 -= base[1 * (size_t)V_ + o];
        s2 -= base[2 * (size_t)V_ + o];
        s3 -= base[3 * (size_t)V_ + o];
        s4 -= base[4 * (size_t)V_ + o];
      }
    }
  }

  __shared__ float red[256];
  red[threadIdx.x] = local;
  __syncthreads();
  for (int s = 128; s > 0; s >>= 1) {
    if (threadIdx.x < s) red[threadIdx.x] += red[threadIdx.x + s];
    __syncthreads();
  }
  if (threadIdx.x == 0) atomicAdd(acc, (double)red[0]);
}

__global__ void finalize_k(const double* __restrict__ acc,
                           float* __restrict__ out) {
  out[0] = (float)(-acc[0] / (double)NTOT);
}

extern "C" void kernel_launch(void* const* d_in, const int* in_sizes, int n_in,
                              void* d_out, int out_size, void* d_ws, size_t ws_size,
                              hipStream_t stream) {
  const float* I = (const float*)d_in[0];   // y_true
  const float* J = (const float*)d_in[1];   // y_pred
  float* out = (float*)d_out;

  double* acc = (double*)d_ws;
  float* F = (float*)((char*)d_ws + 256);   // 5 fields x V_ floats = 98.3 MB

  hipMemsetAsync(d_ws, 0, 256, stream);

  dim3 g1(W_ / TW, H_ / TH, D_);            // 5 x 6 x 160
  const int p2_blocks = (D_ / CHUNK) * (H_ * W_) / 256;  // 600

  for (int b = 0; b < 2; ++b) {
    const float* Ib = I + (size_t)b * V_;
    const float* Jb = J + (size_t)b * V_;
    pass1_wh<<<g1, 256, 0, stream>>>(Ib, Jb, F);
    pass2_d<<<p2_blocks, 256, 0, stream>>>(F, acc);
  }
  finalize_k<<<1, 1, 0, stream>>>(acc, out);
}

// Round 2
// 227.833 us; speedup vs baseline: 1.1516x; 1.1516x over previous
//
#include <hip/hip_runtime.h>

#define D_ 160
#define H_ 192
#define W_ 160
#define HW_ (H_*W_)
#define V_ (D_*H_*W_)
#define NTOT (2*V_)

#define TW 32           // tile width  (W dim)
#define TH 16           // tile height (H dim)
#define DC 32           // D-chunk per block
#define RW 40           // TW + 8 halo
#define RH 24           // TH + 8 halo
#define NCHUNK (D_/DC)  // 5

// ---------------------------------------------------------------------------
// Fully fused separable 9x9x9 box filter + NCC.
// Block: 256 threads, owns a TWxTH tile, marches DC+8 slices in D.
// Per slice: stage I,J halo -> LDS; W-dir 9-sum of 5 product fields;
// H-dir 9-sum; D-dir handled by per-thread 9-deep register ring + running sum.
// ---------------------------------------------------------------------------
__global__ __launch_bounds__(256) void ncc_fused(const float* __restrict__ I,
                                                 const float* __restrict__ J,
                                                 double* __restrict__ acc) {
  __shared__ float2 sIJ[RH][RW];      // staged {I,J} slice with halo (7.7 KB)
  __shared__ float4 ws4[RH][TW];      // W-summed fields 0-3 (12.3 KB, 16B aligned)
  __shared__ float  ws1[RH][TW];      // W-summed field 4   (3.1 KB)
  __shared__ float  red[256];

  const int tid = threadIdx.x;
  const int w0 = blockIdx.x * TW;               // 5 tiles
  const int h0 = blockIdx.y * TH;               // 12 tiles
  const int c0 = (blockIdx.z % NCHUNK) * DC;    // D-chunk start
  const int batch = blockIdx.z / NCHUNK;        // 2 batches

  const float* Ib = I + (size_t)batch * V_;
  const float* Jb = J + (size_t)batch * V_;

  const int tx = tid & 31;            // owned column in tile
  const int ty = tid >> 5;            // 0..7 -> owns rows ty and ty+8

  // D-direction ring buffers + running window sums, per owned position.
  float ring[2][5][9];
  float sum[2][5];
#pragma unroll
  for (int p = 0; p < 2; ++p)
#pragma unroll
    for (int f = 0; f < 5; ++f) {
      sum[p][f] = 0.f;
#pragma unroll
      for (int k = 0; k < 9; ++k) ring[p][f][k] = 0.f;
    }

  float local = 0.f;
  const float inv = 1.f / 729.f;

  for (int step = 0; step < DC + 8; ++step) {
    const int s = c0 - 4 + step;      // global slice index being staged

    // ---- stage slice s (zero outside volume) ----
    const bool dv = (s >= 0) && (s < D_);
    const float* Ip = Ib + (size_t)(dv ? s : 0) * HW_;
    const float* Jp = Jb + (size_t)(dv ? s : 0) * HW_;
    if (tid < RH * 10) {              // 24 rows x 10 float4-quads
      const int r  = tid / 10;
      const int q  = tid % 10;
      const int h  = h0 - 4 + r;
      const int wq = w0 - 4 + q * 4;  // multiple of 4 -> 16B aligned
      float4 a = {0.f, 0.f, 0.f, 0.f}, b = {0.f, 0.f, 0.f, 0.f};
      const bool hv = dv && ((unsigned)h < (unsigned)H_);
      if (hv && wq >= 0 && wq + 3 < W_) {
        a = *(const float4*)(Ip + h * W_ + wq);
        b = *(const float4*)(Jp + h * W_ + wq);
      } else if (hv) {
        float av[4] = {0.f,0.f,0.f,0.f}, bv[4] = {0.f,0.f,0.f,0.f};
#pragma unroll
        for (int e = 0; e < 4; ++e) {
          int w = wq + e;
          if ((unsigned)w < (unsigned)W_) { av[e] = Ip[h*W_+w]; bv[e] = Jp[h*W_+w]; }
        }
        a = make_float4(av[0],av[1],av[2],av[3]);
        b = make_float4(bv[0],bv[1],bv[2],bv[3]);
      }
      sIJ[r][q*4+0] = make_float2(a.x, b.x);
      sIJ[r][q*4+1] = make_float2(a.y, b.y);
      sIJ[r][q*4+2] = make_float2(a.z, b.z);
      sIJ[r][q*4+3] = make_float2(a.w, b.w);
    }
    __syncthreads();

    // ---- W-direction 9-sum of the 5 fields (24x32 positions, 3/thread) ----
#pragma unroll
    for (int k = 0; k < 3; ++k) {
      const int pos = tid + k * 256;
      const int row = pos >> 5, col = pos & 31;
      float s0 = 0.f, s1 = 0.f, s2 = 0.f, s3 = 0.f, s4 = 0.f;
#pragma unroll
      for (int t = 0; t < 9; ++t) {
        const float2 p = sIJ[row][col + t];
        s0 += p.x; s1 += p.y; s2 += p.x*p.x; s3 += p.y*p.y; s4 += p.x*p.y;
      }
      ws4[row][col] = make_float4(s0, s1, s2, s3);
      ws1[row][col] = s4;
    }
    __syncthreads();

    // ---- H-direction 9-sum for owned positions, then D ring update ----
    float hv[2][5];
#pragma unroll
    for (int p = 0; p < 2; ++p) {
      const int hh = ty + p * 8;
      float v0 = 0.f, v1 = 0.f, v2 = 0.f, v3 = 0.f, v4 = 0.f;
#pragma unroll
      for (int t = 0; t < 9; ++t) {
        const float4 a4 = ws4[hh + t][tx];
        v0 += a4.x; v1 += a4.y; v2 += a4.z; v3 += a4.w;
        v4 += ws1[hh + t][tx];
      }
      hv[p][0] = v0; hv[p][1] = v1; hv[p][2] = v2; hv[p][3] = v3; hv[p][4] = v4;
    }

    const bool emit = (step >= 8);    // output slice d = c0 + step - 8
#pragma unroll
    for (int p = 0; p < 2; ++p) {
      float S[5];
#pragma unroll
      for (int f = 0; f < 5; ++f) {
        sum[p][f] += hv[p][f] - ring[p][f][0];
#pragma unroll
        for (int k = 0; k < 8; ++k) ring[p][f][k] = ring[p][f][k+1];
        ring[p][f][8] = hv[p][f];
        S[f] = sum[p][f];
      }
      if (emit) {
        const float uI = S[0] * inv, uJ = S[1] * inv;
        const float cross = S[4] - uJ*S[0] - uI*S[1] + uI*uJ*729.f;
        const float Iv = S[2] - 2.f*uI*S[0] + uI*uI*729.f;
        const float Jv = S[3] - 2.f*uJ*S[1] + uJ*uJ*729.f;
        local += cross * cross / (Iv * Jv + 1e-5f);
      }
    }
    // No barrier needed here: next stage writes sIJ (W-readers already past
    // sync2); next W-write to ws is fenced by next iteration's sync1.
  }

  // ---- block reduction -> global double accumulator ----
  red[tid] = local;
  __syncthreads();
  for (int s2 = 128; s2 > 0; s2 >>= 1) {
    if (tid < s2) red[tid] += red[tid + s2];
    __syncthreads();
  }
  if (tid == 0) atomicAdd(acc, (double)red[0]);
}

__global__ void finalize_k(const double* __restrict__ acc,
                           float* __restrict__ out) {
  out[0] = (float)(-acc[0] / (double)NTOT);
}

extern "C" void kernel_launch(void* const* d_in, const int* in_sizes, int n_in,
                              void* d_out, int out_size, void* d_ws, size_t ws_size,
                              hipStream_t stream) {
  const float* I = (const float*)d_in[0];   // y_true
  const float* J = (const float*)d_in[1];   // y_pred
  float* out = (float*)d_out;
  double* acc = (double*)d_ws;

  hipMemsetAsync(d_ws, 0, 8, stream);

  dim3 grid(W_ / TW, H_ / TH, NCHUNK * 2);  // 5 x 12 x 10 = 600 blocks
  ncc_fused<<<grid, 256, 0, stream>>>(I, J, acc);
  finalize_k<<<1, 1, 0, stream>>>(acc, out);
}

// Round 3
// 172.122 us; speedup vs baseline: 1.5243x; 1.3237x over previous
//
#include <hip/hip_runtime.h>

#define D_ 160
#define H_ 192
#define W_ 160
#define HW_ (H_*W_)
#define V_ (D_*H_*W_)
#define NTOT (2*V_)

#define TW 32
#define TH 16
#define DC 20
#define NCHUNK (D_/DC)    // 8
#define RH 24             // TH + 8 halo
#define RWP 41            // 40 cols + 1 pad (breaks bank aliasing)
#define NSTEP (DC+10)     // 30: pipeline depth 2 + D halo 8
#define NBLOCKS (5*12*NCHUNK*2)   // 960

// ---------------------------------------------------------------------------
// Fully fused separable 9x9x9 box filter + NCC, software-pipelined.
// Per step t (ONE barrier):
//   A: global->reg loads for slice s=c0-4+t
//   B: W-dir 9-sums of slice t-1 (register sliding window, runs of 4)
//   C: H-dir 9-sums of slice t-2 (runs of 2) + per-thread D ring + emit
//   D: reg->LDS write of staged slice
// ---------------------------------------------------------------------------
__global__ __launch_bounds__(256, 3) void ncc_fused(const float* __restrict__ I,
                                                    const float* __restrict__ J,
                                                    float* __restrict__ bsum) {
  __shared__ float2 sIJ[2][RH][RWP];   // staged {I,J}
  __shared__ float4 ws4[2][RH][TW];    // W-sums fields 0-3
  __shared__ float  ws1[2][RH][TW];    // W-sums field 4
  __shared__ float  red[256];

  const int tid = threadIdx.x;
  const int w0 = blockIdx.x * TW;               // 5
  const int h0 = blockIdx.y * TH;               // 12
  const int c0 = (blockIdx.z % NCHUNK) * DC;    // 8 chunks
  const int batch = blockIdx.z / NCHUNK;        // 2

  const float* Ib = I + (size_t)batch * V_;
  const float* Jb = J + (size_t)batch * V_;

  // A/D: stager mapping (tid < 240): 24 rows x 10 float4-quads
  const int sr  = tid / 10;
  const int sq  = tid % 10;
  const int sh  = h0 - 4 + sr;
  const int swq = w0 - 4 + sq * 4;
  const bool s_hv   = (unsigned)sh < (unsigned)H_;
  const bool s_fast = s_hv && (swq >= 0) && (swq + 3 < W_);
  const size_t s_off = (size_t)(s_hv ? sh : 0) * W_ + (s_fast ? swq : 0);

  // B: W-phase mapping (tid < 192): 24 rows x 8 runs of 4
  const int br = tid >> 3;
  const int bc = (tid & 7) * 4;

  // C: H-phase mapping: col tx, rows hb and hb+1
  const int tx = tid & 31;
  const int hb = (tid >> 5) * 2;     // 0..14

  float ring[2][5][9];
  float sum[2][5];
#pragma unroll
  for (int p = 0; p < 2; ++p)
#pragma unroll
    for (int f = 0; f < 5; ++f) {
      sum[p][f] = 0.f;
#pragma unroll
      for (int k = 0; k < 9; ++k) ring[p][f][k] = 0.f;
    }

  float local = 0.f;
  float4 ra = {0,0,0,0}, rb = {0,0,0,0};

  for (int t = 0; t < NSTEP; ++t) {
    // ---- A: issue global loads for slice s = c0-4+t ----
    const int s = c0 - 4 + t;
    if (t < DC + 8 && tid < 240) {
      ra = make_float4(0,0,0,0); rb = make_float4(0,0,0,0);
      if (s >= 0 && s < D_ && s_hv) {
        const float* Ip = Ib + (size_t)s * HW_ + s_off;
        const float* Jp = Jb + (size_t)s * HW_ + s_off;
        if (s_fast) {
          ra = *(const float4*)Ip;
          rb = *(const float4*)Jp;
        } else {
          float av[4] = {0,0,0,0}, bv[4] = {0,0,0,0};
#pragma unroll
          for (int e = 0; e < 4; ++e) {
            int w = swq + e;
            if ((unsigned)w < (unsigned)W_) {
              av[e] = Ib[(size_t)s * HW_ + sh * W_ + w];
              bv[e] = Jb[(size_t)s * HW_ + sh * W_ + w];
            }
          }
          ra = make_float4(av[0],av[1],av[2],av[3]);
          rb = make_float4(bv[0],bv[1],bv[2],bv[3]);
        }
      }
    }

    // ---- B: W-dir 9-sums of slice t-1 from sIJ[(t+1)&1] -> ws[t&1] ----
    if (t >= 1 && t < DC + 9 && tid < 192) {
      const float2* S = sIJ[(t + 1) & 1][br];
      float4* W4 = ws4[t & 1][br];
      float*  W1 = ws1[t & 1][br];
      float2 keep[4];
      float s0 = 0.f, s1 = 0.f, s2 = 0.f, s3 = 0.f, s4 = 0.f;
#pragma unroll
      for (int k = 0; k < 9; ++k) {
        const float2 p = S[bc + k];
        if (k < 4) keep[k] = p;
        s0 += p.x; s1 += p.y; s2 += p.x*p.x; s3 += p.y*p.y; s4 += p.x*p.y;
      }
      W4[bc] = make_float4(s0, s1, s2, s3);
      W1[bc] = s4;
#pragma unroll
      for (int m = 1; m < 4; ++m) {
        const float2 e = S[bc + 8 + m];
        const float2 l = keep[m - 1];
        s0 += e.x - l.x;
        s1 += e.y - l.y;
        s2 += e.x*e.x - l.x*l.x;
        s3 += e.y*e.y - l.y*l.y;
        s4 += e.x*e.y - l.x*l.y;
        W4[bc + m] = make_float4(s0, s1, s2, s3);
        W1[bc + m] = s4;
      }
    }

    // ---- C: H-dir 9-sums of slice t-2 from ws[(t+1)&1] + D ring ----
    if (t >= 2) {
      const int wb = (t + 1) & 1;
      float v0 = 0.f, v1 = 0.f, v2 = 0.f, v3 = 0.f, v4 = 0.f;
      float4 k4; float k1v;
#pragma unroll
      for (int k = 0; k < 9; ++k) {
        const float4 a4 = ws4[wb][hb + k][tx];
        const float  a1 = ws1[wb][hb + k][tx];
        if (k == 0) { k4 = a4; k1v = a1; }
        v0 += a4.x; v1 += a4.y; v2 += a4.z; v3 += a4.w; v4 += a1;
      }
      const float4 t4 = ws4[wb][hb + 9][tx];
      const float  t1 = ws1[wb][hb + 9][tx];
      float hv[2][5];
      hv[0][0] = v0; hv[0][1] = v1; hv[0][2] = v2; hv[0][3] = v3; hv[0][4] = v4;
      hv[1][0] = v0 + t4.x - k4.x;
      hv[1][1] = v1 + t4.y - k4.y;
      hv[1][2] = v2 + t4.z - k4.z;
      hv[1][3] = v3 + t4.w - k4.w;
      hv[1][4] = v4 + t1   - k1v;

      const bool emit = (t >= 10);
#pragma unroll
      for (int p = 0; p < 2; ++p) {
        float S5[5];
#pragma unroll
        for (int f = 0; f < 5; ++f) {
          sum[p][f] += hv[p][f] - ring[p][f][0];
#pragma unroll
          for (int k = 0; k < 8; ++k) ring[p][f][k] = ring[p][f][k + 1];
          ring[p][f][8] = hv[p][f];
          S5[f] = sum[p][f];
        }
        if (emit) {
          const float inv = 1.f / 729.f;
          const float cross = S5[4] - S5[0] * S5[1] * inv;
          const float Iv    = S5[2] - S5[0] * S5[0] * inv;
          const float Jv    = S5[3] - S5[1] * S5[1] * inv;
          local += cross * cross * __builtin_amdgcn_rcpf(Iv * Jv + 1e-5f);
        }
      }
    }

    // ---- D: write staged regs -> sIJ[t&1] ----
    if (t < DC + 8 && tid < 240) {
      float2* row = sIJ[t & 1][sr];
      row[sq*4+0] = make_float2(ra.x, rb.x);
      row[sq*4+1] = make_float2(ra.y, rb.y);
      row[sq*4+2] = make_float2(ra.z, rb.z);
      row[sq*4+3] = make_float2(ra.w, rb.w);
    }

    __syncthreads();
  }

  // ---- block reduction -> per-block partial (no atomic, no memset) ----
  red[tid] = local;
  __syncthreads();
  for (int s2 = 128; s2 > 0; s2 >>= 1) {
    if (tid < s2) red[tid] += red[tid + s2];
    __syncthreads();
  }
  if (tid == 0) {
    const int bid = (blockIdx.z * 12 + blockIdx.y) * 5 + blockIdx.x;
    bsum[bid] = red[0];
  }
}

__global__ __launch_bounds__(256) void finalize_k(const float* __restrict__ bsum,
                                                  float* __restrict__ out) {
  __shared__ double red[256];
  double d = 0.0;
  for (int i = threadIdx.x; i < NBLOCKS; i += 256) d += (double)bsum[i];
  red[threadIdx.x] = d;
  __syncthreads();
  for (int s = 128; s > 0; s >>= 1) {
    if (threadIdx.x < s) red[threadIdx.x] += red[threadIdx.x + s];
    __syncthreads();
  }
  if (threadIdx.x == 0) out[0] = (float)(-red[0] / (double)NTOT);
}

extern "C" void kernel_launch(void* const* d_in, const int* in_sizes, int n_in,
                              void* d_out, int out_size, void* d_ws, size_t ws_size,
                              hipStream_t stream) {
  const float* I = (const float*)d_in[0];   // y_true
  const float* J = (const float*)d_in[1];   // y_pred
  float* out = (float*)d_out;
  float* bsum = (float*)d_ws;               // 960 floats

  dim3 grid(W_ / TW, H_ / TH, NCHUNK * 2);  // 5 x 12 x 16 = 960 blocks
  ncc_fused<<<grid, 256, 0, stream>>>(I, J, bsum);
  finalize_k<<<1, 256, 0, stream>>>(bsum, out);
}

// Round 4
// 170.486 us; speedup vs baseline: 1.5390x; 1.0096x over previous
//
#include <hip/hip_runtime.h>

#define D_ 160
#define H_ 192
#define W_ 160
#define HW_ (H_*W_)
#define V_ (D_*H_*W_)
#define NTOT (2*V_)

#define TW 32
#define TH 16
#define DC 20
#define NCHUNK (D_/DC)    // 8
#define RH 24             // TH + 8 halo
#define RWP 41            // 40 cols + 1 pad (sIJ: b64 reads at 4/double-bank = free)
#define TWP 33            // 32 cols + 1 pad (ws: kills the 4q%8 quad-bank aliasing)
#define NSTEP (DC+10)     // 30: pipeline depth 2 + D halo 8
#define NBLOCKS (5*12*NCHUNK*2)   // 960

// ---------------------------------------------------------------------------
// Fully fused separable 9x9x9 box filter + NCC, software-pipelined.
// Per step t (ONE barrier):
//   A: global->reg loads for slice s=c0-4+t
//   B: W-dir 9-sums of slice t-1 (register sliding window, runs of 4)
//   C: H-dir 9-sums of slice t-2 (runs of 2) + per-thread D ring + emit
//   D: reg->LDS write of staged slice
// ws stride padded to 33: B-writes land on quad-bank (br+4q+m)%8 (uniform),
// ws1 on bank (br+4q+m)%32 (<=2/bank) -- conflict-free per m136 rules.
// ---------------------------------------------------------------------------
__global__ __launch_bounds__(256, 3) void ncc_fused(const float* __restrict__ I,
                                                    const float* __restrict__ J,
                                                    float* __restrict__ bsum) {
  __shared__ float2 sIJ[2][RH][RWP];   // staged {I,J}  15.7 KB
  __shared__ float4 ws4[2][RH][TWP];   // W-sums f0-3   25.3 KB
  __shared__ float  ws1[2][RH][TWP];   // W-sums f4      6.3 KB
  __shared__ float  red[256];

  const int tid = threadIdx.x;
  const int w0 = blockIdx.x * TW;               // 5
  const int h0 = blockIdx.y * TH;               // 12
  const int c0 = (blockIdx.z % NCHUNK) * DC;    // 8 chunks
  const int batch = blockIdx.z / NCHUNK;        // 2

  const float* Ib = I + (size_t)batch * V_;
  const float* Jb = J + (size_t)batch * V_;

  // A/D: stager mapping (tid < 240): 24 rows x 10 float4-quads
  const int sr  = tid / 10;
  const int sq  = tid % 10;
  const int sh  = h0 - 4 + sr;
  const int swq = w0 - 4 + sq * 4;
  const bool s_hv   = (unsigned)sh < (unsigned)H_;
  const bool s_fast = s_hv && (swq >= 0) && (swq + 3 < W_);
  const size_t s_row = (size_t)(s_hv ? sh : 0) * W_;

  // B: W-phase mapping (tid < 192): 24 rows x 8 runs of 4
  const int br = tid >> 3;
  const int bc = (tid & 7) * 4;

  // C: H-phase mapping: col tx, rows hb and hb+1
  const int tx = tid & 31;
  const int hb = (tid >> 5) * 2;     // 0..14

  float ring[2][5][9];
  float sum[2][5];
#pragma unroll
  for (int p = 0; p < 2; ++p)
#pragma unroll
    for (int f = 0; f < 5; ++f) {
      sum[p][f] = 0.f;
#pragma unroll
      for (int k = 0; k < 9; ++k) ring[p][f][k] = 0.f;
    }

  float local = 0.f;
  float4 ra = {0,0,0,0}, rb = {0,0,0,0};

  for (int t = 0; t < NSTEP; ++t) {
    // ---- A: issue global loads for slice s = c0-4+t ----
    const int s = c0 - 4 + t;
    if (t < DC + 8 && tid < 240) {
      ra = make_float4(0,0,0,0); rb = make_float4(0,0,0,0);
      if (s >= 0 && s < D_ && s_hv) {
        const float* IpRow = Ib + (size_t)s * HW_ + s_row;
        const float* JpRow = Jb + (size_t)s * HW_ + s_row;
        if (s_fast) {
          ra = *(const float4*)(IpRow + swq);
          rb = *(const float4*)(JpRow + swq);
        } else {
          float av[4] = {0,0,0,0}, bv[4] = {0,0,0,0};
#pragma unroll
          for (int e = 0; e < 4; ++e) {
            int w = swq + e;
            if ((unsigned)w < (unsigned)W_) { av[e] = IpRow[w]; bv[e] = JpRow[w]; }
          }
          ra = make_float4(av[0],av[1],av[2],av[3]);
          rb = make_float4(bv[0],bv[1],bv[2],bv[3]);
        }
      }
    }

    // ---- B: W-dir 9-sums of slice t-1 from sIJ[(t+1)&1] -> ws[t&1] ----
    if (t >= 1 && t < DC + 9 && tid < 192) {
      const float2* S = sIJ[(t + 1) & 1][br];
      float4* W4 = ws4[t & 1][br];
      float*  W1 = ws1[t & 1][br];
      float2 keep[4];
      float s0 = 0.f, s1 = 0.f, s2 = 0.f, s3 = 0.f, s4 = 0.f;
#pragma unroll
      for (int k = 0; k < 9; ++k) {
        const float2 p = S[bc + k];
        if (k < 4) keep[k] = p;
        s0 += p.x; s1 += p.y; s2 += p.x*p.x; s3 += p.y*p.y; s4 += p.x*p.y;
      }
      W4[bc] = make_float4(s0, s1, s2, s3);
      W1[bc] = s4;
#pragma unroll
      for (int m = 1; m < 4; ++m) {
        const float2 e = S[bc + 8 + m];
        const float2 l = keep[m - 1];
        s0 += e.x - l.x;
        s1 += e.y - l.y;
        s2 += e.x*e.x - l.x*l.x;
        s3 += e.y*e.y - l.y*l.y;
        s4 += e.x*e.y - l.x*l.y;
        W4[bc + m] = make_float4(s0, s1, s2, s3);
        W1[bc + m] = s4;
      }
    }

    // ---- C: H-dir 9-sums of slice t-2 from ws[(t+1)&1] + D ring ----
    if (t >= 2) {
      const int wb = (t + 1) & 1;
      float v0 = 0.f, v1 = 0.f, v2 = 0.f, v3 = 0.f, v4 = 0.f;
      float4 k4; float k1v;
#pragma unroll
      for (int k = 0; k < 9; ++k) {
        const float4 a4 = ws4[wb][hb + k][tx];
        const float  a1 = ws1[wb][hb + k][tx];
        if (k == 0) { k4 = a4; k1v = a1; }
        v0 += a4.x; v1 += a4.y; v2 += a4.z; v3 += a4.w; v4 += a1;
      }
      const float4 t4 = ws4[wb][hb + 9][tx];
      const float  t1 = ws1[wb][hb + 9][tx];
      float hv[2][5];
      hv[0][0] = v0; hv[0][1] = v1; hv[0][2] = v2; hv[0][3] = v3; hv[0][4] = v4;
      hv[1][0] = v0 + t4.x - k4.x;
      hv[1][1] = v1 + t4.y - k4.y;
      hv[1][2] = v2 + t4.z - k4.z;
      hv[1][3] = v3 + t4.w - k4.w;
      hv[1][4] = v4 + t1   - k1v;

      const bool emit = (t >= 10);
#pragma unroll
      for (int p = 0; p < 2; ++p) {
        float S5[5];
#pragma unroll
        for (int f = 0; f < 5; ++f) {
          sum[p][f] += hv[p][f] - ring[p][f][0];
#pragma unroll
          for (int k = 0; k < 8; ++k) ring[p][f][k] = ring[p][f][k + 1];
          ring[p][f][8] = hv[p][f];
          S5[f] = sum[p][f];
        }
        if (emit) {
          const float inv = 1.f / 729.f;
          const float cross = S5[4] - S5[0] * S5[1] * inv;
          const float Iv    = S5[2] - S5[0] * S5[0] * inv;
          const float Jv    = S5[3] - S5[1] * S5[1] * inv;
          local += cross * cross * __builtin_amdgcn_rcpf(Iv * Jv + 1e-5f);
        }
      }
    }

    // ---- D: write staged regs -> sIJ[t&1] ----
    if (t < DC + 8 && tid < 240) {
      float2* row = sIJ[t & 1][sr];
      row[sq*4+0] = make_float2(ra.x, rb.x);
      row[sq*4+1] = make_float2(ra.y, rb.y);
      row[sq*4+2] = make_float2(ra.z, rb.z);
      row[sq*4+3] = make_float2(ra.w, rb.w);
    }

    __syncthreads();
  }

  // ---- block reduction -> per-block partial (no atomic, no memset) ----
  red[tid] = local;
  __syncthreads();
  for (int s2 = 128; s2 > 0; s2 >>= 1) {
    if (tid < s2) red[tid] += red[tid + s2];
    __syncthreads();
  }
  if (tid == 0) {
    const int bid = (blockIdx.z * 12 + blockIdx.y) * 5 + blockIdx.x;
    bsum[bid] = red[0];
  }
}

__global__ __launch_bounds__(256) void finalize_k(const float* __restrict__ bsum,
                                                  float* __restrict__ out) {
  __shared__ double red[256];
  double d = 0.0;
  for (int i = threadIdx.x; i < NBLOCKS; i += 256) d += (double)bsum[i];
  red[threadIdx.x] = d;
  __syncthreads();
  for (int s = 128; s > 0; s >>= 1) {
    if (threadIdx.x < s) red[threadIdx.x] += red[threadIdx.x + s];
    __syncthreads();
  }
  if (threadIdx.x == 0) out[0] = (float)(-red[0] / (double)NTOT);
}

extern "C" void kernel_launch(void* const* d_in, const int* in_sizes, int n_in,
                              void* d_out, int out_size, void* d_ws, size_t ws_size,
                              hipStream_t stream) {
  const float* I = (const float*)d_in[0];   // y_true
  const float* J = (const float*)d_in[1];   // y_pred
  float* out = (float*)d_out;
  float* bsum = (float*)d_ws;               // 960 floats

  dim3 grid(W_ / TW, H_ / TH, NCHUNK * 2);  // 5 x 12 x 16 = 960 blocks
  ncc_fused<<<grid, 256, 0, stream>>>(I, J, bsum);
  finalize_k<<<1, 256, 0, stream>>>(bsum, out);
}